// Round 3
// baseline (312.728 us; speedup 1.0000x reference)
//
#include <hip/hip_runtime.h>
#include <hip/hip_bf16.h>

// Problem constants (B=16, T=2048 fixed by setup_inputs)
constexpr int NB = 16;
constexpr int NT = 2048;
constexpr int KPROP = 2000;
constexpr int CAND_CAP = 8192;          // expected ~4-5K candidates/batch
constexpr int HIST_U32 = NB * 2048;     // 32768 words

// ---------------------------------------------------------------------------
// Workspace layout (bytes), total ~1.18 MB:
//   0      : nS[16]       (int)
//   64     : nE[16]       (int)
//   128    : selAll[16]   (int)
//   192    : P[16]        (uint)  -- level-0 bucket id (bits>>20)
//   256    : need[16]     (int)
//   320    : candCnt[16]  (int)
//   512    : hist[16][2048] u32   (131072 B)
//   131584 : sIdx[16][2048] int
//   262656 : sVal[16][2048] f32
//   393728 : eIdx[16][2048] int   (position-sorted ascending)
//   524800 : eVal[16][2048] f32
//   655872 : cand[16][8192] u32   (flat = s*2048+e; score recomputed later)
// ---------------------------------------------------------------------------

// Anchor selection with ORDERED compaction (prefix scan, deterministic,
// position-sorted output) + zeroing of hist & per-batch scalars.
__global__ void k_select(const float* __restrict__ start, const float* __restrict__ end,
                         int* nS, int* nE, int* selAll, unsigned* P, int* need, int* candCnt,
                         unsigned* hist, int* sIdx, float* sVal, int* eIdx, float* eVal) {
    int b = blockIdx.x, which = blockIdx.y;
    const float* p = (which ? end : start) + (size_t)b * NT;
    int* nArr = which ? nE : nS;
    int* idxArr = (which ? eIdx : sIdx) + b * NT;
    float* valArr = (which ? eVal : sVal) + b * NT;
    int tid = threadIdx.x;

    // cooperative zero of hist region + per-batch scalars
    int gid = (which * NB + b) * 256 + tid;               // 0..8191
    for (int h = gid; h < HIST_U32; h += NB * 2 * 256) hist[h] = 0u;
    if (tid == 0 && which == 0) { selAll[b] = 0; P[b] = 0u; need[b] = 0; candCnt[b] = 0; }

    int t0 = tid * 8;
    float v[8];
    *(float4*)&v[0] = *(const float4*)&p[t0];
    *(float4*)&v[4] = *(const float4*)&p[t0 + 4];

    // row max
    __shared__ float red[256];
    float m = v[0];
    #pragma unroll
    for (int k = 1; k < 8; k++) m = fmaxf(m, v[k]);
    red[tid] = m;
    __syncthreads();
    for (int s = 128; s > 0; s >>= 1) {
        if (tid < s) red[tid] = fmaxf(red[tid], red[tid + s]);
        __syncthreads();
    }
    float thr = 0.5f * red[0];

    float prev = (tid == 0)   ? -1.0f : p[t0 - 1];   // t==0: rise forced true (v >= 0 > -1)
    float next = (tid == 255) ? -1.0f : p[t0 + 8];   // t==2047: fall forced true

    bool flag[8];
    int c = 0;
    #pragma unroll
    for (int k = 0; k < 8; k++) {
        float pv = (k == 0) ? prev : v[k - 1];
        float nv = (k == 7) ? next : v[k + 1];
        bool f = ((v[k] > pv) && (v[k] > nv)) || (v[k] > thr);
        flag[k] = f;
        c += f;
    }

    // block-wide inclusive scan of per-thread counts (Hillis-Steele)
    __shared__ int sc[256];
    sc[tid] = c;
    __syncthreads();
    for (int off = 1; off < 256; off <<= 1) {
        int val = (tid >= off) ? sc[tid - off] : 0;
        __syncthreads();
        sc[tid] += val;
        __syncthreads();
    }
    int pos = sc[tid] - c;   // exclusive offset
    #pragma unroll
    for (int k = 0; k < 8; k++) {
        if (flag[k]) { idxArr[pos] = t0 + k; valArr[pos] = v[k]; pos++; }
    }
    if (tid == 255) nArr[b] = sc[255];
}

// Level-0 histogram of score bits[30:20] over all VALID pairs (binary-searched
// suffix, since eIdx is position-sorted), fused with zeroing the FIRST half of out.
__global__ void k_hist0(const int* __restrict__ nS, const int* __restrict__ nE,
                        const int* __restrict__ sIdx, const float* __restrict__ sVal,
                        const int* __restrict__ eIdx, const float* __restrict__ eVal,
                        unsigned* __restrict__ hist, float4* __restrict__ out4) {
    int b = blockIdx.y, tid = threadIdx.x;
    int blockId = b * gridDim.x + blockIdx.x;             // 0..1023
    {   // zero first 8,388,608 float4 (134 MB): 8192 per block, 32 per thread
        float4 z = make_float4(0.f, 0.f, 0.f, 0.f);
        size_t base = (size_t)blockId * 8192 + tid;
        #pragma unroll
        for (int it = 0; it < 32; it++) out4[base + it * 256] = z;
    }
    __shared__ unsigned shist[2048];
    for (int c = tid; c < 2048; c += 256) shist[c] = 0u;
    __syncthreads();

    int ns = nS[b], ne = nE[b];
    const int* si = sIdx + b * NT;
    const float* sv = sVal + b * NT;
    const int* ei = eIdx + b * NT;
    const float* ev = eVal + b * NT;

    for (int i = blockIdx.x; i < ns; i += gridDim.x) {
        int s = si[i];
        float svi = sv[i];
        int lo = 0, hi = ne;                               // first j with ei[j] >= s
        while (lo < hi) { int mid = (lo + hi) >> 1; if (ei[mid] < s) lo = mid + 1; else hi = mid; }
        for (int j = lo + tid; j < ne; j += 256) {
            unsigned bits = __float_as_uint(svi * ev[j]);  // positive -> bits>>20 < 2048
            atomicAdd(&shist[bits >> 20], 1u);
        }
    }
    __syncthreads();
    unsigned* h = hist + b * 2048;
    for (int c = tid; c < 2048; c += 256) {
        unsigned x = shist[c];
        if (x) atomicAdd(&h[c], x);
    }
}

// Descending scan of the level-0 histogram -> threshold bucket V0 + remaining need.
__global__ void k_scan(const unsigned* __restrict__ hist, int* selAll, unsigned* P, int* need) {
    int b = blockIdx.x, tid = threadIdx.x;
    const unsigned* h = hist + b * 2048;
    __shared__ int cs[256];
    int base = tid * 8, sum = 0;
    #pragma unroll
    for (int c = 0; c < 8; c++) sum += (int)h[base + c];
    cs[tid] = sum;
    __syncthreads();
    if (tid == 0) {
        int nd = KPROP, acc = 0, tc = -1;
        for (int t = 255; t >= 0; t--) {
            if (acc + cs[t] >= nd) { tc = t; break; }
            acc += cs[t];
        }
        if (tc < 0) { selAll[b] = 1; }
        else {
            int found = tc * 8;
            for (int c = tc * 8 + 7; c >= tc * 8; c--) {
                int cnt = (int)h[c];
                if (acc + cnt >= nd) { found = c; break; }
                acc += cnt;
            }
            P[b] = (unsigned)found;      // bucket id = bits>>20
            need[b] = nd - acc;          // in [1, h[found]]
        }
    }
}

// Collect flat indices of candidates (bucket >= V0), fused with zeroing the
// SECOND half of out. Never writes 1.0 (no race with its own fill).
__global__ void k_collect(const int* __restrict__ nS, const int* __restrict__ nE,
                          const int* __restrict__ sIdx, const float* __restrict__ sVal,
                          const int* __restrict__ eIdx, const float* __restrict__ eVal,
                          const int* __restrict__ selAll, const unsigned* __restrict__ P,
                          int* candCnt, unsigned* cand, float4* __restrict__ out4) {
    int b = blockIdx.y, tid = threadIdx.x;
    int blockId = b * gridDim.x + blockIdx.x;
    {   // zero second 8,388,608 float4
        float4 z = make_float4(0.f, 0.f, 0.f, 0.f);
        size_t base = 8388608 + (size_t)blockId * 8192 + tid;
        #pragma unroll
        for (int it = 0; it < 32; it++) out4[base + it * 256] = z;
    }
    if (selAll[b]) return;                                 // k_final handles slow path
    unsigned V0 = P[b];
    int ns = nS[b], ne = nE[b];
    const int* si = sIdx + b * NT;
    const float* sv = sVal + b * NT;
    const int* ei = eIdx + b * NT;
    const float* ev = eVal + b * NT;

    for (int i = blockIdx.x; i < ns; i += gridDim.x) {
        int s = si[i];
        float svi = sv[i];
        int lo = 0, hi = ne;
        while (lo < hi) { int mid = (lo + hi) >> 1; if (ei[mid] < s) lo = mid + 1; else hi = mid; }
        for (int j = lo + tid; j < ne; j += 256) {
            unsigned bits = __float_as_uint(svi * ev[j]);
            if ((bits >> 20) >= V0) {
                int pos = atomicAdd(&candCnt[b], 1);
                if (pos < CAND_CAP) cand[b * CAND_CAP + pos] = (unsigned)(s * NT + ei[j]);
            }
        }
    }
}

// Exact selection among candidates: two more 10-bit radix levels (scores
// recomputed from start/end), write 1.0 for winners, flat-rank tie-break.
__global__ void k_final(const float* __restrict__ start, const float* __restrict__ end,
                        const int* __restrict__ nS, const int* __restrict__ nE,
                        const int* __restrict__ sIdx, const int* __restrict__ eIdx,
                        const int* __restrict__ selAll, const unsigned* __restrict__ P,
                        const int* __restrict__ need, const int* __restrict__ candCnt,
                        const unsigned* __restrict__ cand, float* __restrict__ out) {
    int b = blockIdx.x, tid = threadIdx.x;
    const float* sp = start + (size_t)b * NT;
    const float* ep = end   + (size_t)b * NT;

    if (selAll[b]) {   // <K valid pairs: all valid pairs become 1.0 (never hit for bench data)
        int ns = nS[b], ne = nE[b];
        const int* si = sIdx + b * NT;
        const int* ei = eIdx + b * NT;
        for (int i = 0; i < ns; i++) {
            int s = si[i];
            int lo = 0, hi = ne;
            while (lo < hi) { int mid = (lo + hi) >> 1; if (ei[mid] < s) lo = mid + 1; else hi = mid; }
            for (int j = lo + tid; j < ne; j += 256) {
                int e = ei[j];
                out[((size_t)b * NT + (e - s)) * NT + s] = 1.0f;
            }
        }
        return;
    }

    int n = min(candCnt[b], CAND_CAP);
    int nd = need[b];
    unsigned V0 = P[b];

    __shared__ unsigned h[1024];
    __shared__ int cs[256];
    __shared__ unsigned tie[1024];
    __shared__ int tieCnt;
    __shared__ unsigned sTmp;
    __shared__ int sNd;

    // ---- level 1: bits[19:10] among in-bucket candidates ----
    for (int c = tid; c < 1024; c += 256) h[c] = 0u;
    __syncthreads();
    for (int k = tid; k < n; k += 256) {
        unsigned flat = cand[b * CAND_CAP + k];
        unsigned bits = __float_as_uint(sp[flat >> 11] * ep[flat & 2047]);
        if ((bits >> 20) == V0) atomicAdd(&h[(bits >> 10) & 1023], 1u);
    }
    __syncthreads();
    { int base = tid * 4, s2 = 0;
      #pragma unroll
      for (int c = 0; c < 4; c++) s2 += (int)h[base + c];
      cs[tid] = s2; }
    __syncthreads();
    if (tid == 0) {
        int acc = 0, tc = 0;
        for (int t = 255; t >= 0; t--) { if (acc + cs[t] >= nd) { tc = t; break; } acc += cs[t]; }
        int found = tc * 4;
        for (int c = tc * 4 + 3; c >= tc * 4; c--) {
            int cnt = (int)h[c];
            if (acc + cnt >= nd) { found = c; break; }
            acc += cnt;
        }
        sTmp = (unsigned)found;  sNd = nd - acc;
    }
    __syncthreads();
    unsigned pref10 = (V0 << 10) | sTmp;
    int nd1 = sNd;

    // ---- level 2: bits[9:0] ----
    for (int c = tid; c < 1024; c += 256) h[c] = 0u;
    __syncthreads();
    for (int k = tid; k < n; k += 256) {
        unsigned flat = cand[b * CAND_CAP + k];
        unsigned bits = __float_as_uint(sp[flat >> 11] * ep[flat & 2047]);
        if ((bits >> 10) == pref10) atomicAdd(&h[bits & 1023], 1u);
    }
    __syncthreads();
    { int base = tid * 4, s2 = 0;
      #pragma unroll
      for (int c = 0; c < 4; c++) s2 += (int)h[base + c];
      cs[tid] = s2; }
    __syncthreads();
    if (tid == 0) {
        int acc = 0, tc = 0;
        for (int t = 255; t >= 0; t--) { if (acc + cs[t] >= nd1) { tc = t; break; } acc += cs[t]; }
        int found = tc * 4;
        for (int c = tc * 4 + 3; c >= tc * 4; c--) {
            int cnt = (int)h[c];
            if (acc + cnt >= nd1) { found = c; break; }
            acc += cnt;
        }
        sTmp = (pref10 << 10) | (unsigned)found;   // exact 32-bit K-th score bits
        sNd  = nd1 - acc;                          // ties still needed at V32
        tieCnt = 0;
    }
    __syncthreads();
    unsigned V32 = sTmp;
    int nd2 = sNd;

    // ---- write winners (> V32), collect exact ties (== V32) ----
    for (int k = tid; k < n; k += 256) {
        unsigned flat = cand[b * CAND_CAP + k];
        int s = flat >> 11, e = flat & 2047;
        unsigned bits = __float_as_uint(sp[s] * ep[e]);
        if (bits > V32) {
            out[((size_t)b * NT + (e - s)) * NT + s] = 1.0f;
        } else if (bits == V32) {
            int pos = atomicAdd(&tieCnt, 1);
            if (pos < 1024) tie[pos] = flat;
        }
    }
    __syncthreads();
    int tn = min(tieCnt, 1024);
    for (int k = tid; k < tn; k += 256) {
        unsigned f = tie[k];
        int rank = 0;
        for (int j = 0; j < tn; j++) rank += (tie[j] < f) ? 1 : 0;
        if (rank < nd2) {                          // lowest flat indices win (lax.top_k)
            int s = f >> 11, e = f & 2047;
            out[((size_t)b * NT + (e - s)) * NT + s] = 1.0f;
        }
    }
}

extern "C" void kernel_launch(void* const* d_in, const int* in_sizes, int n_in,
                              void* d_out, int out_size, void* d_ws, size_t ws_size,
                              hipStream_t stream) {
    const float* start = (const float*)d_in[0];
    const float* end   = (const float*)d_in[1];
    // d_in[2] (actionness) unused by the reference.
    float* out = (float*)d_out;
    char* ws = (char*)d_ws;

    int*      nS      = (int*)     (ws + 0);
    int*      nE      = (int*)     (ws + 64);
    int*      selAll  = (int*)     (ws + 128);
    unsigned* P       = (unsigned*)(ws + 192);
    int*      need    = (int*)     (ws + 256);
    int*      candCnt = (int*)     (ws + 320);
    unsigned* hist    = (unsigned*)(ws + 512);
    int*      sIdx    = (int*)     (ws + 131584);
    float*    sVal    = (float*)   (ws + 262656);
    int*      eIdx    = (int*)     (ws + 393728);
    float*    eVal    = (float*)   (ws + 524800);
    unsigned* cand    = (unsigned*)(ws + 655872);

    // 1) anchor selection (ordered compaction) + zero hist/scalars
    k_select<<<dim3(NB, 2), 256, 0, stream>>>(start, end, nS, nE, selAll, P, need, candCnt,
                                              hist, sIdx, sVal, eIdx, eVal);
    // 2) level-0 histogram over valid pairs, fused with zeroing first half of out
    k_hist0<<<dim3(64, NB), 256, 0, stream>>>(nS, nE, sIdx, sVal, eIdx, eVal, hist,
                                              (float4*)out);
    // 3) find threshold bucket
    k_scan<<<NB, 256, 0, stream>>>(hist, selAll, P, need);
    // 4) collect candidates (bucket >= V0), fused with zeroing second half of out
    k_collect<<<dim3(64, NB), 256, 0, stream>>>(nS, nE, sIdx, sVal, eIdx, eVal, selAll, P,
                                                candCnt, cand, (float4*)out);
    // 5) exact selection + scatter of 1.0s
    k_final<<<NB, 256, 0, stream>>>(start, end, nS, nE, sIdx, eIdx, selAll, P, need,
                                    candCnt, cand, out);
}

// Round 4
// 162.249 us; speedup vs baseline: 1.9275x; 1.9275x over previous
//
#include <hip/hip_runtime.h>
#include <hip/hip_bf16.h>

// Problem constants (B=16, T=2048 fixed by setup_inputs)
constexpr int NB = 16;
constexpr int NT = 2048;
constexpr int KPROP = 2000;
constexpr int CAND_CAP = 8192;          // observed ~4-5K candidates/batch
constexpr int HIST_U32 = NB * 2048;     // 32768 words
constexpr int CC_STRIDE = 32;           // candCnt padded: 1 counter per 128 B

// ---------------------------------------------------------------------------
// Workspace layout (bytes), total ~1.19 MB:
//   0       : nS[16]          (int)
//   64      : nE[16]          (int)
//   128     : selAll[16]      (int)
//   192     : P[16]           (uint)  -- level-0 bucket id (bits>>20)
//   256     : need[16]        (int)
//   512     : candCnt[16*32]  (int)   -- padded, index b*32 (2048 B)
//   4096    : hist[16][2048]  u32     (131072 B)
//   135168  : sIdx[16][2048]  int
//   266240  : sVal[16][2048]  f32
//   397312  : eIdx[16][2048]  int     (position-sorted ascending)
//   528384  : eVal[16][2048]  f32
//   659456  : cand[16][8192]  u32     (flat = s*2048+e)
// ---------------------------------------------------------------------------

// Anchor selection with ORDERED compaction (prefix scan, deterministic,
// position-sorted output) + zeroing of hist & per-batch scalars.
__global__ void k_select(const float* __restrict__ start, const float* __restrict__ end,
                         int* nS, int* nE, int* selAll, unsigned* P, int* need, int* candCnt,
                         unsigned* hist, int* sIdx, float* sVal, int* eIdx, float* eVal) {
    int b = blockIdx.x, which = blockIdx.y;
    const float* p = (which ? end : start) + (size_t)b * NT;
    int* nArr = which ? nE : nS;
    int* idxArr = (which ? eIdx : sIdx) + b * NT;
    float* valArr = (which ? eVal : sVal) + b * NT;
    int tid = threadIdx.x;

    // cooperative zero of hist region + padded counters + per-batch scalars
    int gid = (which * NB + b) * 256 + tid;               // 0..8191
    for (int h = gid; h < HIST_U32; h += NB * 2 * 256) hist[h] = 0u;
    if (gid < NB * CC_STRIDE) candCnt[gid] = 0;
    if (tid == 0 && which == 0) { selAll[b] = 0; P[b] = 0u; need[b] = 0; }

    int t0 = tid * 8;
    float v[8];
    *(float4*)&v[0] = *(const float4*)&p[t0];
    *(float4*)&v[4] = *(const float4*)&p[t0 + 4];

    // row max
    __shared__ float red[256];
    float m = v[0];
    #pragma unroll
    for (int k = 1; k < 8; k++) m = fmaxf(m, v[k]);
    red[tid] = m;
    __syncthreads();
    for (int s = 128; s > 0; s >>= 1) {
        if (tid < s) red[tid] = fmaxf(red[tid], red[tid + s]);
        __syncthreads();
    }
    float thr = 0.5f * red[0];

    float prev = (tid == 0)   ? -1.0f : p[t0 - 1];   // t==0: rise forced true
    float next = (tid == 255) ? -1.0f : p[t0 + 8];   // t==2047: fall forced true

    bool flag[8];
    int c = 0;
    #pragma unroll
    for (int k = 0; k < 8; k++) {
        float pv = (k == 0) ? prev : v[k - 1];
        float nv = (k == 7) ? next : v[k + 1];
        bool f = ((v[k] > pv) && (v[k] > nv)) || (v[k] > thr);
        flag[k] = f;
        c += f;
    }

    // block-wide inclusive scan of per-thread counts (Hillis-Steele)
    __shared__ int sc[256];
    sc[tid] = c;
    __syncthreads();
    for (int off = 1; off < 256; off <<= 1) {
        int val = (tid >= off) ? sc[tid - off] : 0;
        __syncthreads();
        sc[tid] += val;
        __syncthreads();
    }
    int pos = sc[tid] - c;   // exclusive offset
    #pragma unroll
    for (int k = 0; k < 8; k++) {
        if (flag[k]) { idxArr[pos] = t0 + k; valArr[pos] = v[k]; pos++; }
    }
    if (tid == 255) nArr[b] = sc[255];
}

// Level-0 histogram of score bits[30:20] over all VALID pairs (binary-searched
// suffix, since eIdx is position-sorted), fused with zeroing ALL of out (268 MB).
__global__ void k_hist0(const int* __restrict__ nS, const int* __restrict__ nE,
                        const int* __restrict__ sIdx, const float* __restrict__ sVal,
                        const int* __restrict__ eIdx, const float* __restrict__ eVal,
                        unsigned* __restrict__ hist, float4* __restrict__ out4) {
    int b = blockIdx.y, tid = threadIdx.x;
    int blockId = b * gridDim.x + blockIdx.x;             // 0..1023
    {   // zero 16,777,216 float4 (268 MB): 16384 per block, 64 per thread
        float4 z = make_float4(0.f, 0.f, 0.f, 0.f);
        size_t base = (size_t)blockId * 16384 + tid;
        #pragma unroll
        for (int it = 0; it < 64; it++) out4[base + it * 256] = z;
    }
    __shared__ unsigned shist[2048];
    for (int c = tid; c < 2048; c += 256) shist[c] = 0u;
    __syncthreads();

    int ns = nS[b], ne = nE[b];
    const int* si = sIdx + b * NT;
    const float* sv = sVal + b * NT;
    const int* ei = eIdx + b * NT;
    const float* ev = eVal + b * NT;

    for (int i = blockIdx.x; i < ns; i += gridDim.x) {
        int s = si[i];
        float svi = sv[i];
        int lo = 0, hi = ne;                               // first j with ei[j] >= s
        while (lo < hi) { int mid = (lo + hi) >> 1; if (ei[mid] < s) lo = mid + 1; else hi = mid; }
        for (int j = lo + tid; j < ne; j += 256) {
            unsigned bits = __float_as_uint(svi * ev[j]);  // in (0,1): bits>>20 < 2048
            atomicAdd(&shist[bits >> 20], 1u);
        }
    }
    __syncthreads();
    unsigned* h = hist + b * 2048;
    for (int c = tid; c < 2048; c += 256) {
        unsigned x = shist[c];
        if (x) atomicAdd(&h[c], x);
    }
}

// Descending scan of the level-0 histogram -> threshold bucket V0 + remaining need.
__global__ void k_scan(const unsigned* __restrict__ hist, int* selAll, unsigned* P, int* need) {
    int b = blockIdx.x, tid = threadIdx.x;
    const unsigned* h = hist + b * 2048;
    __shared__ int cs[256];
    int base = tid * 8, sum = 0;
    #pragma unroll
    for (int c = 0; c < 8; c++) sum += (int)h[base + c];
    cs[tid] = sum;
    __syncthreads();
    if (tid == 0) {
        int nd = KPROP, acc = 0, tc = -1;
        for (int t = 255; t >= 0; t--) {
            if (acc + cs[t] >= nd) { tc = t; break; }
            acc += cs[t];
        }
        if (tc < 0) { selAll[b] = 1; }
        else {
            int found = tc * 8;
            for (int c = tc * 8 + 7; c >= tc * 8; c--) {
                int cnt = (int)h[c];
                if (acc + cnt >= nd) { found = c; break; }
                acc += cnt;
            }
            P[b] = (unsigned)found;      // bucket id = bits>>20
            need[b] = nd - acc;          // in [1, h[found]]
        }
    }
}

// Collect flat indices of candidates (bucket >= V0). LDS-buffered: one global
// atomic per block (plus rare guarded spills), not one per candidate.
__global__ void k_collect(const int* __restrict__ nS, const int* __restrict__ nE,
                          const int* __restrict__ sIdx, const float* __restrict__ sVal,
                          const int* __restrict__ eIdx, const float* __restrict__ eVal,
                          const int* __restrict__ selAll, const unsigned* __restrict__ P,
                          int* candCnt, unsigned* cand) {
    constexpr int LCAP = 4096;
    __shared__ unsigned lbuf[LCAP];
    __shared__ int lcnt;
    __shared__ int sBase;
    int b = blockIdx.y, tid = threadIdx.x;
    if (selAll[b]) return;
    if (tid == 0) lcnt = 0;
    __syncthreads();

    unsigned V0 = P[b];
    int ns = nS[b], ne = nE[b];
    const int* si = sIdx + b * NT;
    const float* sv = sVal + b * NT;
    const int* ei = eIdx + b * NT;
    const float* ev = eVal + b * NT;
    int* cc = candCnt + b * CC_STRIDE;

    for (int i = blockIdx.x; i < ns; i += gridDim.x) {
        int s = si[i];
        float svi = sv[i];
        int lo = 0, hi = ne;
        while (lo < hi) { int mid = (lo + hi) >> 1; if (ei[mid] < s) lo = mid + 1; else hi = mid; }
        for (int j = lo + tid; j < ne; j += 256) {
            unsigned bits = __float_as_uint(svi * ev[j]);
            if ((bits >> 20) >= V0) {
                int pos = atomicAdd(&lcnt, 1);
                if (pos < LCAP) {
                    lbuf[pos] = (unsigned)(s * NT + ei[j]);
                } else {                                   // rare spill path
                    int g = atomicAdd(cc, 1);
                    if (g < CAND_CAP) cand[b * CAND_CAP + g] = (unsigned)(s * NT + ei[j]);
                }
            }
        }
    }
    __syncthreads();
    int cnt = min(lcnt, LCAP);
    if (tid == 0) sBase = atomicAdd(cc, cnt);
    __syncthreads();
    int base = sBase;
    for (int k = tid; k < cnt; k += 256) {
        int g = base + k;
        if (g < CAND_CAP) cand[b * CAND_CAP + g] = lbuf[k];
    }
}

// Exact selection among candidates: two more 10-bit radix levels (scores
// recomputed from start/end), write 1.0 for winners, flat-rank tie-break.
__global__ void k_final(const float* __restrict__ start, const float* __restrict__ end,
                        const int* __restrict__ nS, const int* __restrict__ nE,
                        const int* __restrict__ sIdx, const int* __restrict__ eIdx,
                        const int* __restrict__ selAll, const unsigned* __restrict__ P,
                        const int* __restrict__ need, const int* __restrict__ candCnt,
                        const unsigned* __restrict__ cand, float* __restrict__ out) {
    int b = blockIdx.x, tid = threadIdx.x;
    const float* sp = start + (size_t)b * NT;
    const float* ep = end   + (size_t)b * NT;

    if (selAll[b]) {   // <K valid pairs: all valid pairs become 1.0
        int ns = nS[b], ne = nE[b];
        const int* si = sIdx + b * NT;
        const int* ei = eIdx + b * NT;
        for (int i = 0; i < ns; i++) {
            int s = si[i];
            int lo = 0, hi = ne;
            while (lo < hi) { int mid = (lo + hi) >> 1; if (ei[mid] < s) lo = mid + 1; else hi = mid; }
            for (int j = lo + tid; j < ne; j += 256) {
                int e = ei[j];
                out[((size_t)b * NT + (e - s)) * NT + s] = 1.0f;
            }
        }
        return;
    }

    int n = min(candCnt[b * CC_STRIDE], CAND_CAP);
    int nd = need[b];
    unsigned V0 = P[b];

    __shared__ unsigned h[1024];
    __shared__ int cs[256];
    __shared__ unsigned tie[1024];
    __shared__ int tieCnt;
    __shared__ unsigned sTmp;
    __shared__ int sNd;

    // ---- level 1: bits[19:10] among in-bucket candidates ----
    for (int c = tid; c < 1024; c += 256) h[c] = 0u;
    __syncthreads();
    for (int k = tid; k < n; k += 256) {
        unsigned flat = cand[b * CAND_CAP + k];
        unsigned bits = __float_as_uint(sp[flat >> 11] * ep[flat & 2047]);
        if ((bits >> 20) == V0) atomicAdd(&h[(bits >> 10) & 1023], 1u);
    }
    __syncthreads();
    { int base = tid * 4, s2 = 0;
      #pragma unroll
      for (int c = 0; c < 4; c++) s2 += (int)h[base + c];
      cs[tid] = s2; }
    __syncthreads();
    if (tid == 0) {
        int acc = 0, tc = 0;
        for (int t = 255; t >= 0; t--) { if (acc + cs[t] >= nd) { tc = t; break; } acc += cs[t]; }
        int found = tc * 4;
        for (int c = tc * 4 + 3; c >= tc * 4; c--) {
            int cnt = (int)h[c];
            if (acc + cnt >= nd) { found = c; break; }
            acc += cnt;
        }
        sTmp = (unsigned)found;  sNd = nd - acc;
    }
    __syncthreads();
    unsigned pref10 = (V0 << 10) | sTmp;
    int nd1 = sNd;

    // ---- level 2: bits[9:0] ----
    for (int c = tid; c < 1024; c += 256) h[c] = 0u;
    __syncthreads();
    for (int k = tid; k < n; k += 256) {
        unsigned flat = cand[b * CAND_CAP + k];
        unsigned bits = __float_as_uint(sp[flat >> 11] * ep[flat & 2047]);
        if ((bits >> 10) == pref10) atomicAdd(&h[bits & 1023], 1u);
    }
    __syncthreads();
    { int base = tid * 4, s2 = 0;
      #pragma unroll
      for (int c = 0; c < 4; c++) s2 += (int)h[base + c];
      cs[tid] = s2; }
    __syncthreads();
    if (tid == 0) {
        int acc = 0, tc = 0;
        for (int t = 255; t >= 0; t--) { if (acc + cs[t] >= nd1) { tc = t; break; } acc += cs[t]; }
        int found = tc * 4;
        for (int c = tc * 4 + 3; c >= tc * 4; c--) {
            int cnt = (int)h[c];
            if (acc + cnt >= nd1) { found = c; break; }
            acc += cnt;
        }
        sTmp = (pref10 << 10) | (unsigned)found;   // exact 32-bit K-th score bits
        sNd  = nd1 - acc;                          // ties still needed at V32
        tieCnt = 0;
    }
    __syncthreads();
    unsigned V32 = sTmp;
    int nd2 = sNd;

    // ---- write winners (> V32), collect exact ties (== V32) ----
    for (int k = tid; k < n; k += 256) {
        unsigned flat = cand[b * CAND_CAP + k];
        int s = flat >> 11, e = flat & 2047;
        unsigned bits = __float_as_uint(sp[s] * ep[e]);
        if (bits > V32) {
            out[((size_t)b * NT + (e - s)) * NT + s] = 1.0f;
        } else if (bits == V32) {
            int pos = atomicAdd(&tieCnt, 1);
            if (pos < 1024) tie[pos] = flat;
        }
    }
    __syncthreads();
    int tn = min(tieCnt, 1024);
    for (int k = tid; k < tn; k += 256) {
        unsigned f = tie[k];
        int rank = 0;
        for (int j = 0; j < tn; j++) rank += (tie[j] < f) ? 1 : 0;
        if (rank < nd2) {                          // lowest flat indices win (lax.top_k)
            int s = f >> 11, e = f & 2047;
            out[((size_t)b * NT + (e - s)) * NT + s] = 1.0f;
        }
    }
}

extern "C" void kernel_launch(void* const* d_in, const int* in_sizes, int n_in,
                              void* d_out, int out_size, void* d_ws, size_t ws_size,
                              hipStream_t stream) {
    const float* start = (const float*)d_in[0];
    const float* end   = (const float*)d_in[1];
    // d_in[2] (actionness) unused by the reference.
    float* out = (float*)d_out;
    char* ws = (char*)d_ws;

    int*      nS      = (int*)     (ws + 0);
    int*      nE      = (int*)     (ws + 64);
    int*      selAll  = (int*)     (ws + 128);
    unsigned* P       = (unsigned*)(ws + 192);
    int*      need    = (int*)     (ws + 256);
    int*      candCnt = (int*)     (ws + 512);     // padded [16*32]
    unsigned* hist    = (unsigned*)(ws + 4096);
    int*      sIdx    = (int*)     (ws + 135168);
    float*    sVal    = (float*)   (ws + 266240);
    int*      eIdx    = (int*)     (ws + 397312);
    float*    eVal    = (float*)   (ws + 528384);
    unsigned* cand    = (unsigned*)(ws + 659456);

    // 1) anchor selection (ordered compaction) + zero hist/counters/scalars
    k_select<<<dim3(NB, 2), 256, 0, stream>>>(start, end, nS, nE, selAll, P, need, candCnt,
                                              hist, sIdx, sVal, eIdx, eVal);
    // 2) level-0 histogram over valid pairs, fused with zeroing ALL of out
    k_hist0<<<dim3(64, NB), 256, 0, stream>>>(nS, nE, sIdx, sVal, eIdx, eVal, hist,
                                              (float4*)out);
    // 3) find threshold bucket
    k_scan<<<NB, 256, 0, stream>>>(hist, selAll, P, need);
    // 4) collect candidates (bucket >= V0), LDS-buffered
    k_collect<<<dim3(32, NB), 256, 0, stream>>>(nS, nE, sIdx, sVal, eIdx, eVal, selAll, P,
                                                candCnt, cand);
    // 5) exact selection + scatter of 1.0s
    k_final<<<NB, 256, 0, stream>>>(start, end, nS, nE, sIdx, eIdx, selAll, P, need,
                                    candCnt, cand, out);
}